// Round 2
// baseline (1197.732 us; speedup 1.0000x reference)
//
#include <hip/hip_runtime.h>
#include <math.h>

constexpr int HD    = 32;     // head dim
constexpr int LW    = 256;    // tokens per window (M * N_CAND)
constexpr int NWIN  = 128;    // number of windows (= B_)
constexpr int ROWS  = NWIN * LW;   // 32768 total rows
constexpr int QKVC  = 384;    // qkv columns
constexpr float SCALE = 0.17677669529663687f;  // 1/sqrt(32)

__device__ inline float dot4(const float4 a, const float4 b) {
  return a.x * b.x + a.y * b.y + a.z * b.z + a.w * b.w;
}

// ---------------- RPE gather: rpe_g[h][i4*64+j4][0:96] ----------------
// s in [0,32): scale*q_rpe   [32,64): k_rpe   [64,96): v_rpe
__global__ __launch_bounds__(256) void rpe_gather_kernel(
    const float* __restrict__ tab, const int* __restrict__ rel_idx,
    float* __restrict__ out)
{
  int gid = blockIdx.x * 256 + threadIdx.x;   // 4*4096*96 = 1,572,864 exact
  int s   = gid % 96;
  int hp  = gid / 96;
  int p   = hp & 4095;
  int h   = hp >> 12;
  float v = tab[(size_t)rel_idx[p] * 384 + h * 96 + s];
  if (s < 32) v *= SCALE;
  out[gid] = v;
}

// ---------------- C[M,N] = A[M,K] @ W[N,K]^T + bias (LDS dbuf v2) -----------
// BM=BN=128, BK=16, 256 threads, 8x8 micro-tile. As/Ws stored transposed
// [k][m] with stride 132 (+4 pad -> bank=(4k+m)%32, staging ~2-way = free).
template <int N, int K>
__global__ __launch_bounds__(256, 4) void gemm_nt_bias_v2(
    const float* __restrict__ A, const float* __restrict__ W,
    const float* __restrict__ bias, float* __restrict__ C)
{
  constexpr int BK  = 16;
  constexpr int NS  = K / BK;
  constexpr int LDP = 132;
  __shared__ float As[2][BK][LDP];
  __shared__ float Ws[2][BK][LDP];

  const int tid  = threadIdx.x;
  const int tx   = tid & 15;          // n-dir, 8 cols each
  const int ty   = tid >> 4;          // m-dir, 8 rows each
  const int srow = tid >> 2;          // staging row 0..63 (+64 for second half)
  const int skk  = (tid & 3) << 2;    // staging k base: 0,4,8,12

  const float* Ag = A + ((size_t)blockIdx.x * 128 + srow) * K + skk;
  const float* Wg = W + ((size_t)blockIdx.y * 128 + srow) * K + skk;

  float4 ra0, ra1, rw0, rw1;
  // prologue: stage 0
  ra0 = *(const float4*)(Ag);
  ra1 = *(const float4*)(Ag + (size_t)64 * K);
  rw0 = *(const float4*)(Wg);
  rw1 = *(const float4*)(Wg + (size_t)64 * K);
  As[0][skk + 0][srow]      = ra0.x; As[0][skk + 1][srow]      = ra0.y;
  As[0][skk + 2][srow]      = ra0.z; As[0][skk + 3][srow]      = ra0.w;
  As[0][skk + 0][srow + 64] = ra1.x; As[0][skk + 1][srow + 64] = ra1.y;
  As[0][skk + 2][srow + 64] = ra1.z; As[0][skk + 3][srow + 64] = ra1.w;
  Ws[0][skk + 0][srow]      = rw0.x; Ws[0][skk + 1][srow]      = rw0.y;
  Ws[0][skk + 2][srow]      = rw0.z; Ws[0][skk + 3][srow]      = rw0.w;
  Ws[0][skk + 0][srow + 64] = rw1.x; Ws[0][skk + 1][srow + 64] = rw1.y;
  Ws[0][skk + 2][srow + 64] = rw1.z; Ws[0][skk + 3][srow + 64] = rw1.w;
  __syncthreads();

  float acc[8][8] = {};

  for (int s = 0; s < NS; ++s) {
    const int cur = s & 1;
    if (s + 1 < NS) {
      const int k0 = (s + 1) * BK;
      ra0 = *(const float4*)(Ag + k0);
      ra1 = *(const float4*)(Ag + (size_t)64 * K + k0);
      rw0 = *(const float4*)(Wg + k0);
      rw1 = *(const float4*)(Wg + (size_t)64 * K + k0);
    }
#pragma unroll
    for (int k = 0; k < BK; ++k) {
      float4 a0 = *(const float4*)&As[cur][k][ty * 8];
      float4 a1 = *(const float4*)&As[cur][k][ty * 8 + 4];
      float4 b0 = *(const float4*)&Ws[cur][k][tx * 8];
      float4 b1 = *(const float4*)&Ws[cur][k][tx * 8 + 4];
      float av[8] = {a0.x, a0.y, a0.z, a0.w, a1.x, a1.y, a1.z, a1.w};
      float bv[8] = {b0.x, b0.y, b0.z, b0.w, b1.x, b1.y, b1.z, b1.w};
#pragma unroll
      for (int i = 0; i < 8; ++i)
#pragma unroll
        for (int j = 0; j < 8; ++j)
          acc[i][j] += av[i] * bv[j];
    }
    if (s + 1 < NS) {
      const int nxt = (s + 1) & 1;
      As[nxt][skk + 0][srow]      = ra0.x; As[nxt][skk + 1][srow]      = ra0.y;
      As[nxt][skk + 2][srow]      = ra0.z; As[nxt][skk + 3][srow]      = ra0.w;
      As[nxt][skk + 0][srow + 64] = ra1.x; As[nxt][skk + 1][srow + 64] = ra1.y;
      As[nxt][skk + 2][srow + 64] = ra1.z; As[nxt][skk + 3][srow + 64] = ra1.w;
      Ws[nxt][skk + 0][srow]      = rw0.x; Ws[nxt][skk + 1][srow]      = rw0.y;
      Ws[nxt][skk + 2][srow]      = rw0.z; Ws[nxt][skk + 3][srow]      = rw0.w;
      Ws[nxt][skk + 0][srow + 64] = rw1.x; Ws[nxt][skk + 1][srow + 64] = rw1.y;
      Ws[nxt][skk + 2][srow + 64] = rw1.z; Ws[nxt][skk + 3][srow + 64] = rw1.w;
      __syncthreads();
    }
  }

  const int crow = blockIdx.x * 128 + ty * 8;
  const int ccol = blockIdx.y * 128 + tx * 8;
  float4 bb0 = *(const float4*)(bias + ccol);
  float4 bb1 = *(const float4*)(bias + ccol + 4);
#pragma unroll
  for (int i = 0; i < 8; ++i) {
    float4 r0, r1;
    r0.x = acc[i][0] + bb0.x; r0.y = acc[i][1] + bb0.y;
    r0.z = acc[i][2] + bb0.z; r0.w = acc[i][3] + bb0.w;
    r1.x = acc[i][4] + bb1.x; r1.y = acc[i][5] + bb1.y;
    r1.z = acc[i][6] + bb1.z; r1.w = acc[i][7] + bb1.w;
    *(float4*)(C + (size_t)(crow + i) * N + ccol)     = r0;
    *(float4*)(C + (size_t)(crow + i) * N + ccol + 4) = r1;
  }
}

// ---------------- fused window attention ----------------
// grid (NWIN, 4 heads), 256 threads: thread = one query row, online softmax.
// S_ij = (q*s)·K_j + (q*s)·k_rpe[i4,j4] + K_j·(s*q_rpe[i4,j4]) + mask[b,i,j]
//      = K_j·u + c0 + mask,  u = q*s + s*q_rpe,  c0 = (q*s)·k_rpe  (per j4)
// out_i = sum_j p_j V_j + sum_j4 pool_j4 * v_rpe[i4,j4]
__global__ __launch_bounds__(256) void attn_kernel(
    const float* __restrict__ qkv, const float* __restrict__ rpeg,
    const float* __restrict__ mask, float* __restrict__ out)
{
  __shared__ float kvs[2 * LW * HD];   // K then V, 64 KB
  const int b = blockIdx.x;
  const int h = blockIdx.y;
  const int tid = threadIdx.x;
  const size_t rowbase = (size_t)b * LW;

  // stage K (cols 128+h*32) and V (cols 256+h*32) into LDS
  for (int it = 0; it < 8; ++it) {
    int f = tid + 256 * it;            // 0..2047
    int j = f >> 3, d4 = f & 7;
    const float* src = qkv + (rowbase + j) * QKVC + h * HD + d4 * 4;
    *(float4*)(&kvs[j * HD + d4 * 4])            = *(const float4*)(src + 128);
    *(float4*)(&kvs[LW * HD + j * HD + d4 * 4])  = *(const float4*)(src + 256);
  }
  __syncthreads();

  const int i  = tid;
  const int i4 = i >> 2;
  float4 q[8];
  {
    const float4* qr = (const float4*)(qkv + (rowbase + i) * QKVC + h * HD);
#pragma unroll
    for (int d = 0; d < 8; ++d) {
      float4 t = qr[d];
      q[d] = make_float4(t.x * SCALE, t.y * SCALE, t.z * SCALE, t.w * SCALE);
    }
  }
  const float4* rp4base =
      (const float4*)(rpeg + ((size_t)h * 4096 + (size_t)i4 * 64) * 96);
  const float* mrow = mask + ((size_t)b * LW + i) * LW;

  float4 acc[8];
#pragma unroll
  for (int d = 0; d < 8; ++d) acc[d] = make_float4(0.f, 0.f, 0.f, 0.f);
  float m_run = -INFINITY, l_run = 0.f;

  for (int j4 = 0; j4 < 64; ++j4) {
    const float4* rp = rp4base + j4 * 24;   // 96 floats
    float4 u[8];
    float c0 = 0.f;
#pragma unroll
    for (int d = 0; d < 8; ++d) {
      float4 sq = rp[d];        // scale * q_rpe
      float4 kr = rp[8 + d];    // k_rpe
      u[d] = make_float4(q[d].x + sq.x, q[d].y + sq.y,
                         q[d].z + sq.z, q[d].w + sq.w);
      c0 += dot4(q[d], kr);
    }
    float4 mv = *(const float4*)(mrow + j4 * 4);
    float mvals[4] = {mv.x, mv.y, mv.z, mv.w};
    float pool = 0.f;
#pragma unroll
    for (int jc = 0; jc < 4; ++jc) {
      const int j = j4 * 4 + jc;
      const float4* kj = (const float4*)(&kvs[j * HD]);
      float s = c0 + mvals[jc];
#pragma unroll
      for (int d = 0; d < 8; ++d) s += dot4(u[d], kj[d]);
      if (s > m_run) {
        float r = __expf(m_run - s);
        m_run = s;
        l_run *= r; pool *= r;
#pragma unroll
        for (int d = 0; d < 8; ++d) {
          acc[d].x *= r; acc[d].y *= r; acc[d].z *= r; acc[d].w *= r;
        }
      }
      float p = __expf(s - m_run);
      l_run += p; pool += p;
      const float4* vj = (const float4*)(&kvs[LW * HD + j * HD]);
#pragma unroll
      for (int d = 0; d < 8; ++d) {
        acc[d].x += p * vj[d].x; acc[d].y += p * vj[d].y;
        acc[d].z += p * vj[d].z; acc[d].w += p * vj[d].w;
      }
    }
#pragma unroll
    for (int d = 0; d < 8; ++d) {
      float4 vr = rp[16 + d];
      acc[d].x += pool * vr.x; acc[d].y += pool * vr.y;
      acc[d].z += pool * vr.z; acc[d].w += pool * vr.w;
    }
  }
  float inv = 1.f / l_run;
  float4* orow = (float4*)(out + (rowbase + i) * (4 * HD) + h * HD);
#pragma unroll
  for (int d = 0; d < 8; ++d)
    orow[d] = make_float4(acc[d].x * inv, acc[d].y * inv,
                          acc[d].z * inv, acc[d].w * inv);
}

extern "C" void kernel_launch(void* const* d_in, const int* in_sizes, int n_in,
                              void* d_out, int out_size, void* d_ws, size_t ws_size,
                              hipStream_t stream) {
  (void)in_sizes; (void)n_in; (void)out_size; (void)ws_size;
  const float* x         = (const float*)d_in[0];
  const float* qkv_w     = (const float*)d_in[1];
  const float* qkv_b     = (const float*)d_in[2];
  const float* rpe_table = (const float*)d_in[3];
  const float* proj_w    = (const float*)d_in[4];
  const float* proj_b    = (const float*)d_in[5];
  const float* attn_mask = (const float*)d_in[6];
  const int*   rel_idx   = (const int*)d_in[7];
  float* out = (float*)d_out;

  float* qkvbuf = (float*)d_ws;                          // 32768*384 fp32 (50.3 MB)
  float* rpeg   = qkvbuf + (size_t)ROWS * QKVC;          // 4*4096*96  (6.3 MB)
  float* attnb  = rpeg + (size_t)4 * 4096 * 96;          // 32768*128  (16.8 MB)

  hipLaunchKernelGGL(rpe_gather_kernel, dim3(6144), dim3(256), 0, stream,
                     rpe_table, rel_idx, rpeg);
  hipLaunchKernelGGL((gemm_nt_bias_v2<QKVC, 128>), dim3(ROWS / 128, QKVC / 128),
                     dim3(256), 0, stream, x, qkv_w, qkv_b, qkvbuf);
  hipLaunchKernelGGL(attn_kernel, dim3(NWIN, 4), dim3(256), 0, stream,
                     qkvbuf, rpeg, attn_mask, attnb);
  hipLaunchKernelGGL((gemm_nt_bias_v2<128, 128>), dim3(ROWS / 128, 1),
                     dim3(256), 0, stream, attnb, proj_w, proj_b, out);
}

// Round 3
// 314.968 us; speedup vs baseline: 3.8027x; 3.8027x over previous
//
#include <hip/hip_runtime.h>
#include <math.h>

constexpr int HD    = 32;     // head dim
constexpr int LW    = 256;    // tokens per window (M * N_CAND)
constexpr int NWIN  = 128;    // number of windows (= B_)
constexpr int ROWS  = NWIN * LW;   // 32768 total rows
constexpr int QKVC  = 384;    // qkv columns
constexpr float SCALE = 0.17677669529663687f;  // 1/sqrt(32)

__device__ inline float dot4(const float4 a, const float4 b) {
  return a.x * b.x + a.y * b.y + a.z * b.z + a.w * b.w;
}

// ---------------- RPE gather: rpe_g[h][i4*64+j4][0:96] ----------------
// s in [0,32): scale*q_rpe   [32,64): k_rpe   [64,96): v_rpe
__global__ __launch_bounds__(256) void rpe_gather_kernel(
    const float* __restrict__ tab, const int* __restrict__ rel_idx,
    float* __restrict__ out)
{
  int gid = blockIdx.x * 256 + threadIdx.x;   // 4*4096*96 = 1,572,864 exact
  int s   = gid % 96;
  int hp  = gid / 96;
  int p   = hp & 4095;
  int h   = hp >> 12;
  float v = tab[(size_t)rel_idx[p] * 384 + h * 96 + s];
  if (s < 32) v *= SCALE;
  out[gid] = v;
}

// ---------------- C[M,N] = A[M,K] @ W[N,K]^T + bias (LDS dbuf v3) -----------
// BM=BN=128, BK=8, 256 threads, 8x8 micro-tile.
// LDS tiles transposed [k][phys(m)], phys(m)=m+(m>>5)*4 (swizzle: the 16
// distinct tx*8 read addrs map 2 lanes/bank-cluster -> conflict-free; staging
// writes 2-way = free). Row stride 144. NO waves-per-EU cap (v2's 64-VGPR
// spill: acc[8][8] went to scratch -> 1.7 GB WRITE_SIZE).
template <int N, int K>
__global__ __launch_bounds__(256) void gemm_nt_bias_v3(
    const float* __restrict__ A, const float* __restrict__ W,
    const float* __restrict__ bias, float* __restrict__ C)
{
  constexpr int BK  = 8;
  constexpr int NS  = K / BK;
  constexpr int LDP = 144;
  __shared__ float As[2][BK][LDP];
  __shared__ float Ws[2][BK][LDP];

  const int tid  = threadIdx.x;
  const int tx   = tid & 15;          // n-dir, 8 cols each
  const int ty   = tid >> 4;          // m-dir, 8 rows each
  const int srow = tid >> 1;          // staging row 0..127
  const int skk  = (tid & 1) << 2;    // staging k base: 0 or 4
  const int sphys = srow + ((srow >> 5) << 2);

  const float* Ag = A + ((size_t)blockIdx.x * 128 + srow) * K + skk;
  const float* Wg = W + ((size_t)blockIdx.y * 128 + srow) * K + skk;

  float4 ra = *(const float4*)(Ag);
  float4 rw = *(const float4*)(Wg);
  As[0][skk + 0][sphys] = ra.x; As[0][skk + 1][sphys] = ra.y;
  As[0][skk + 2][sphys] = ra.z; As[0][skk + 3][sphys] = ra.w;
  Ws[0][skk + 0][sphys] = rw.x; Ws[0][skk + 1][sphys] = rw.y;
  Ws[0][skk + 2][sphys] = rw.z; Ws[0][skk + 3][sphys] = rw.w;
  __syncthreads();

  const int mA = ty * 8; const int pA = mA + ((mA >> 5) << 2);
  const int mB = tx * 8; const int pB = mB + ((mB >> 5) << 2);

  float acc[8][8] = {};

  for (int s = 0; s < NS; ++s) {
    const int cur = s & 1;
    if (s + 1 < NS) {
      const int k0 = (s + 1) * BK;
      ra = *(const float4*)(Ag + k0);
      rw = *(const float4*)(Wg + k0);
    }
#pragma unroll
    for (int k = 0; k < BK; ++k) {
      float4 a0 = *(const float4*)&As[cur][k][pA];
      float4 a1 = *(const float4*)&As[cur][k][pA + 4];
      float4 b0 = *(const float4*)&Ws[cur][k][pB];
      float4 b1 = *(const float4*)&Ws[cur][k][pB + 4];
      float av[8] = {a0.x, a0.y, a0.z, a0.w, a1.x, a1.y, a1.z, a1.w};
      float bv[8] = {b0.x, b0.y, b0.z, b0.w, b1.x, b1.y, b1.z, b1.w};
#pragma unroll
      for (int i = 0; i < 8; ++i)
#pragma unroll
        for (int j = 0; j < 8; ++j)
          acc[i][j] += av[i] * bv[j];
    }
    if (s + 1 < NS) {
      const int nxt = (s + 1) & 1;
      As[nxt][skk + 0][sphys] = ra.x; As[nxt][skk + 1][sphys] = ra.y;
      As[nxt][skk + 2][sphys] = ra.z; As[nxt][skk + 3][sphys] = ra.w;
      Ws[nxt][skk + 0][sphys] = rw.x; Ws[nxt][skk + 1][sphys] = rw.y;
      Ws[nxt][skk + 2][sphys] = rw.z; Ws[nxt][skk + 3][sphys] = rw.w;
      __syncthreads();
    }
  }

  const int crow = blockIdx.x * 128 + ty * 8;
  const int ccol = blockIdx.y * 128 + tx * 8;
  float4 bb0 = *(const float4*)(bias + ccol);
  float4 bb1 = *(const float4*)(bias + ccol + 4);
#pragma unroll
  for (int i = 0; i < 8; ++i) {
    float4 r0, r1;
    r0.x = acc[i][0] + bb0.x; r0.y = acc[i][1] + bb0.y;
    r0.z = acc[i][2] + bb0.z; r0.w = acc[i][3] + bb0.w;
    r1.x = acc[i][4] + bb1.x; r1.y = acc[i][5] + bb1.y;
    r1.z = acc[i][6] + bb1.z; r1.w = acc[i][7] + bb1.w;
    *(float4*)(C + (size_t)(crow + i) * N + ccol)     = r0;
    *(float4*)(C + (size_t)(crow + i) * N + ccol + 4) = r1;
  }
}

// ---------------- fused window attention ----------------
// grid (NWIN, 4 heads), 256 threads: thread = one query row, online softmax.
// S_ij = (q*s)·K_j + (q*s)·k_rpe[i4,j4] + K_j·(s*q_rpe[i4,j4]) + mask[b,i,j]
//      = K_j·u + c0 + mask,  u = q*s + s*q_rpe,  c0 = (q*s)·k_rpe  (per j4)
// out_i = sum_j p_j V_j + sum_j4 pool_j4 * v_rpe[i4,j4]
__global__ __launch_bounds__(256) void attn_kernel(
    const float* __restrict__ qkv, const float* __restrict__ rpeg,
    const float* __restrict__ mask, float* __restrict__ out)
{
  __shared__ float kvs[2 * LW * HD];   // K then V, 64 KB
  const int b = blockIdx.x;
  const int h = blockIdx.y;
  const int tid = threadIdx.x;
  const size_t rowbase = (size_t)b * LW;

  // stage K (cols 128+h*32) and V (cols 256+h*32) into LDS
  for (int it = 0; it < 8; ++it) {
    int f = tid + 256 * it;            // 0..2047
    int j = f >> 3, d4 = f & 7;
    const float* src = qkv + (rowbase + j) * QKVC + h * HD + d4 * 4;
    *(float4*)(&kvs[j * HD + d4 * 4])            = *(const float4*)(src + 128);
    *(float4*)(&kvs[LW * HD + j * HD + d4 * 4])  = *(const float4*)(src + 256);
  }
  __syncthreads();

  const int i  = tid;
  const int i4 = i >> 2;
  float4 q[8];
  {
    const float4* qr = (const float4*)(qkv + (rowbase + i) * QKVC + h * HD);
#pragma unroll
    for (int d = 0; d < 8; ++d) {
      float4 t = qr[d];
      q[d] = make_float4(t.x * SCALE, t.y * SCALE, t.z * SCALE, t.w * SCALE);
    }
  }
  const float4* rp4base =
      (const float4*)(rpeg + ((size_t)h * 4096 + (size_t)i4 * 64) * 96);
  const float* mrow = mask + ((size_t)b * LW + i) * LW;

  float4 acc[8];
#pragma unroll
  for (int d = 0; d < 8; ++d) acc[d] = make_float4(0.f, 0.f, 0.f, 0.f);
  float m_run = -INFINITY, l_run = 0.f;

  for (int j4 = 0; j4 < 64; ++j4) {
    const float4* rp = rp4base + j4 * 24;   // 96 floats
    float4 u[8];
    float c0 = 0.f;
#pragma unroll
    for (int d = 0; d < 8; ++d) {
      float4 sq = rp[d];        // scale * q_rpe
      float4 kr = rp[8 + d];    // k_rpe
      u[d] = make_float4(q[d].x + sq.x, q[d].y + sq.y,
                         q[d].z + sq.z, q[d].w + sq.w);
      c0 += dot4(q[d], kr);
    }
    float4 mv = *(const float4*)(mrow + j4 * 4);
    float mvals[4] = {mv.x, mv.y, mv.z, mv.w};
    float pool = 0.f;
#pragma unroll
    for (int jc = 0; jc < 4; ++jc) {
      const int j = j4 * 4 + jc;
      const float4* kj = (const float4*)(&kvs[j * HD]);
      float s = c0 + mvals[jc];
#pragma unroll
      for (int d = 0; d < 8; ++d) s += dot4(u[d], kj[d]);
      if (s > m_run) {
        float r = __expf(m_run - s);
        m_run = s;
        l_run *= r; pool *= r;
#pragma unroll
        for (int d = 0; d < 8; ++d) {
          acc[d].x *= r; acc[d].y *= r; acc[d].z *= r; acc[d].w *= r;
        }
      }
      float p = __expf(s - m_run);
      l_run += p; pool += p;
      const float4* vj = (const float4*)(&kvs[LW * HD + j * HD]);
#pragma unroll
      for (int d = 0; d < 8; ++d) {
        acc[d].x += p * vj[d].x; acc[d].y += p * vj[d].y;
        acc[d].z += p * vj[d].z; acc[d].w += p * vj[d].w;
      }
    }
#pragma unroll
    for (int d = 0; d < 8; ++d) {
      float4 vr = rp[16 + d];
      acc[d].x += pool * vr.x; acc[d].y += pool * vr.y;
      acc[d].z += pool * vr.z; acc[d].w += pool * vr.w;
    }
  }
  float inv = 1.f / l_run;
  float4* orow = (float4*)(out + (rowbase + i) * (4 * HD) + h * HD);
#pragma unroll
  for (int d = 0; d < 8; ++d)
    orow[d] = make_float4(acc[d].x * inv, acc[d].y * inv,
                          acc[d].z * inv, acc[d].w * inv);
}

extern "C" void kernel_launch(void* const* d_in, const int* in_sizes, int n_in,
                              void* d_out, int out_size, void* d_ws, size_t ws_size,
                              hipStream_t stream) {
  (void)in_sizes; (void)n_in; (void)out_size; (void)ws_size;
  const float* x         = (const float*)d_in[0];
  const float* qkv_w     = (const float*)d_in[1];
  const float* qkv_b     = (const float*)d_in[2];
  const float* rpe_table = (const float*)d_in[3];
  const float* proj_w    = (const float*)d_in[4];
  const float* proj_b    = (const float*)d_in[5];
  const float* attn_mask = (const float*)d_in[6];
  const int*   rel_idx   = (const int*)d_in[7];
  float* out = (float*)d_out;

  float* qkvbuf = (float*)d_ws;                          // 32768*384 fp32 (50.3 MB)
  float* rpeg   = qkvbuf + (size_t)ROWS * QKVC;          // 4*4096*96  (6.3 MB)
  float* attnb  = rpeg + (size_t)4 * 4096 * 96;          // 32768*128  (16.8 MB)

  hipLaunchKernelGGL(rpe_gather_kernel, dim3(6144), dim3(256), 0, stream,
                     rpe_table, rel_idx, rpeg);
  hipLaunchKernelGGL((gemm_nt_bias_v3<QKVC, 128>), dim3(ROWS / 128, QKVC / 128),
                     dim3(256), 0, stream, x, qkv_w, qkv_b, qkvbuf);
  hipLaunchKernelGGL(attn_kernel, dim3(NWIN, 4), dim3(256), 0, stream,
                     qkvbuf, rpeg, attn_mask, attnb);
  hipLaunchKernelGGL((gemm_nt_bias_v3<128, 128>), dim3(ROWS / 128, 1),
                     dim3(256), 0, stream, attnb, proj_w, proj_b, out);
}